// Round 10
// baseline (4323.982 us; speedup 1.0000x reference)
//
#include <hip/hip_runtime.h>
#include <hip/hip_fp16.h>

#define N_NODES 500000
#define N_EDGES 16000000
#define NB 1954          // ceil(N_NODES/256)
#define NPB_LOG 9
#define NPB 512          // nodes per bucket
#define NBUCK 977        // ceil(N_NODES/NPB)
#define NBUCK_PAD 1024
#define CH 16384         // edges per bucket_scatter block (LDS-staged)
#define NSB 977          // ceil(N_EDGES/CH)

// slice-major sub-sort within each bucket for phased L2 locality:
// src < 500000 < 2^19; slice = src>>15 in [0,15] (32768 nodes per slice).
// fine_sort key = (slice << 9) | node_in_bucket  -> per-bucket edge array is
// slice-major, enabling EDGE-PARALLEL phase scans.
#define SLICE_SHIFT 15
#define NSLICE 16
#define NKEY (NPB * NSLICE)   // 8192 counters = 32 KB LDS

// phased layer kernels: one bucket per block, 977 blocks, 4 blocks/CU
#define LGRID NBUCK

// distributed two-level barrier: 16 sub-counters (128 B apart) + master + flag
#define BAR_SUBC 16
#define BAR_REC_INTS 1024                // 4 KB per barrier record
#define BAR_MASTER 512
#define BAR_FLAG 544
#define ENTRY_BUDGET 1500
#define PHASE_BUDGET 400

// ---------- fp16 pack/unpack helpers (fp32 math everywhere else) ----------
__device__ __forceinline__ float2 up2(int p) {
    __half2 h = *reinterpret_cast<__half2*>(&p);
    return __half22float2(h);
}
__device__ __forceinline__ int pk2(float a, float b) {
    __half2 h = __floats2half2_rn(a, b);
    return *reinterpret_cast<int*>(&h);
}

// ---------- performance-only distributed barrier (bounded spin) ------------
// quotas handle LGRID not divisible by BAR_SUBC
__device__ __forceinline__ void barrier_arrive(int* rec, int bid) {
    int c = bid & (BAR_SUBC - 1);
    int quota = LGRID / BAR_SUBC + (c < (LGRID & (BAR_SUBC - 1)) ? 1 : 0);
    int r = __hip_atomic_fetch_add(&rec[c * 32], 1,
                                   __ATOMIC_RELAXED, __HIP_MEMORY_SCOPE_AGENT);
    if (r == quota - 1) {
        int mr = __hip_atomic_fetch_add(&rec[BAR_MASTER], 1,
                                        __ATOMIC_RELAXED, __HIP_MEMORY_SCOPE_AGENT);
        if (mr == BAR_SUBC - 1)
            __hip_atomic_store(&rec[BAR_FLAG], 1,
                               __ATOMIC_RELAXED, __HIP_MEMORY_SCOPE_AGENT);
    }
}
__device__ __forceinline__ bool barrier_wait(int* rec, int budget) {
    int spins = 0;
    while (__hip_atomic_load(&rec[BAR_FLAG],
                             __ATOMIC_RELAXED, __HIP_MEMORY_SCOPE_AGENT) == 0) {
        if (++spins > budget) return false;
        __builtin_amdgcn_s_sleep(8);
    }
    return true;
}

// ============================================================================
// Two-level counting sort (LDS atomics) -> slice-major packed edges (Sp)
// ============================================================================

__global__ void bucket_hist(const int* __restrict__ dst, int* __restrict__ ghist) {
    __shared__ int lhist[NBUCK_PAD];
    for (int t = threadIdx.x; t < NBUCK_PAD; t += 256) lhist[t] = 0;
    __syncthreads();
    int stride = gridDim.x * 256;
    for (int i = blockIdx.x * 256 + threadIdx.x; i < N_EDGES; i += stride) {
        atomicAdd(&lhist[dst[i] >> NPB_LOG], 1);
    }
    __syncthreads();
    for (int t = threadIdx.x; t < NBUCK_PAD; t += 256) {
        int c = lhist[t];
        if (c) atomicAdd(&ghist[t], c);
    }
}

__global__ void bucket_scan(int* __restrict__ gcur, int* __restrict__ bbase) {
    __shared__ int s[256];
    int t = threadIdx.x;
    int v[4], sum = 0, loc[4];
#pragma unroll
    for (int j = 0; j < 4; ++j) {
        v[j] = gcur[t * 4 + j];
        loc[j] = sum;
        sum += v[j];
    }
    s[t] = sum;
    __syncthreads();
    for (int o = 1; o < 256; o <<= 1) {
        int x = (t >= o) ? s[t - o] : 0;
        __syncthreads();
        s[t] += x;
        __syncthreads();
    }
    int excl = s[t] - sum;
#pragma unroll
    for (int j = 0; j < 4; ++j) {
        int e = excl + loc[j];
        bbase[t * 4 + j] = e;
        gcur[t * 4 + j] = e;
    }
    if (t == 255) bbase[NBUCK_PAD] = s[255];
}

// bucket_scatter: LDS-staged local sort -> coalesced global run writes.
__global__ __launch_bounds__(256) void bucket_scatter(
        const int* __restrict__ src, const int* __restrict__ dst,
        int* __restrict__ gcur, int* __restrict__ P) {
    __shared__ int lP[CH];             // 64 KB staged packed values
    __shared__ int lhist[NBUCK_PAD];   // counts -> local cursor
    __shared__ int lexcl[NBUCK_PAD];   // local exclusive prefix
    __shared__ int gbase[NBUCK_PAD];   // global base per bucket
    __shared__ int sscan[256];
    int t = threadIdx.x;
    for (int j = t; j < NBUCK_PAD; j += 256) lhist[j] = 0;
    __syncthreads();

    int e0 = blockIdx.x * CH;
    int e1 = min(e0 + CH, N_EDGES);
    for (int i = e0 + t; i < e1; i += 256) {
        atomicAdd(&lhist[dst[i] >> NPB_LOG], 1);
    }
    __syncthreads();

    int base4 = t * 4;
    int c[4], sum = 0;
#pragma unroll
    for (int j = 0; j < 4; ++j) { c[j] = lhist[base4 + j]; sum += c[j]; }
#pragma unroll
    for (int j = 0; j < 4; ++j) {
        gbase[base4 + j] = c[j] ? atomicAdd(&gcur[base4 + j], c[j]) : 0;
    }
    sscan[t] = sum;
    __syncthreads();
    for (int o = 1; o < 256; o <<= 1) {
        int x = (t >= o) ? sscan[t - o] : 0;
        __syncthreads();
        sscan[t] += x;
        __syncthreads();
    }
    int run = sscan[t] - sum;
#pragma unroll
    for (int j = 0; j < 4; ++j) {
        lexcl[base4 + j] = run;
        lhist[base4 + j] = run;   // becomes the scatter cursor
        run += c[j];
    }
    __syncthreads();

    for (int i = e0 + t; i < e1; i += 256) {
        int d = dst[i];
        int s = src[i];
        int b = d >> NPB_LOG;
        int pos = atomicAdd(&lhist[b], 1);
        lP[pos] = ((d & (NPB - 1)) << 19) | s;
    }
    __syncthreads();

    int wave = t >> 6, lane = t & 63;
    for (int b = wave; b < NBUCK_PAD; b += 4) {
        int lb = lexcl[b];
        int cnt = lhist[b] - lb;   // cursor - base = count
        int gb = gbase[b];
        for (int j = lane; j < cnt; j += 64) {
            P[gb + j] = lP[lb + j];
        }
    }
}

// fine_sort v4: key = (slice << 9) | node_in_bucket (slice-major).
// Outputs: Sp packed (node<<19|src) slice-major per bucket, deg[node].
// NOTE: writes ONLY deg (outside P region) and Sp. sliceoff is computed by
// the slice_off kernel AFTER this one -- round-9's bug was writing sliceoff
// (which overlays P) from inside fine_sort while other blocks still read P.
__global__ void fine_sort(const int* __restrict__ P, const int* __restrict__ bbase,
                          int* __restrict__ deg, int* __restrict__ Sp) {
    __shared__ int hist[NKEY];   // 32 KB
    __shared__ int sscan[256];
    int t = threadIdx.x;
    int b = blockIdx.x;
    int bb = bbase[b];
    int be = bbase[b + 1];
    int node0 = b << NPB_LOG;

    for (int j = t; j < NKEY; j += 256) hist[j] = 0;
    __syncthreads();
    for (int j = bb + t; j < be; j += 256) {
        int p = P[j];
        int n = p >> 19;
        int sl = (p & 0x7FFFF) >> SLICE_SHIFT;
        atomicAdd(&hist[(sl << NPB_LOG) | n], 1);
    }
    __syncthreads();

    // per-node degree = sum over slices
#pragma unroll
    for (int rep = 0; rep < 2; ++rep) {
        int n = t + rep * 256;
        int d = 0;
#pragma unroll
        for (int sl = 0; sl < NSLICE; ++sl) d += hist[(sl << NPB_LOG) | n];
        int ng = node0 + n;
        if (ng < N_NODES) deg[ng] = d;
    }
    __syncthreads();

    // scan over 8192 counters: thread t owns keys [32t, 32t+32)
    int base = t * 32;
    int sum = 0;
#pragma unroll
    for (int j = 0; j < 32; ++j) sum += hist[base + j];
    sscan[t] = sum;
    __syncthreads();
    for (int o = 1; o < 256; o <<= 1) {
        int x = (t >= o) ? sscan[t - o] : 0;
        __syncthreads();
        sscan[t] += x;
        __syncthreads();
    }
    int run = sscan[t] - sum;
#pragma unroll
    for (int j = 0; j < 32; ++j) {
        int c = hist[base + j];
        hist[base + j] = run;
        run += c;
    }
    __syncthreads();

    for (int j = bb + t; j < be; j += 256) {
        int p = P[j];
        int n = p >> 19;
        int sl = (p & 0x7FFFF) >> SLICE_SHIFT;
        int pos = atomicAdd(&hist[(sl << NPB_LOG) | n], 1);
        Sp[bb + pos] = p;
    }
}

// slice_off: per bucket, recover the 16 slice start offsets from Sp.
// Runs AFTER fine_sort (P dead) so the soff overlay inside P is safe.
__global__ __launch_bounds__(256) void slice_off(const int* __restrict__ bbase,
        const int* __restrict__ Sp, int* __restrict__ soff) {
    __shared__ int h[NSLICE];
    int t = threadIdx.x, b = blockIdx.x;
    if (t < NSLICE) h[t] = 0;
    __syncthreads();
    int bb = bbase[b], be = bbase[b + 1];
    for (int j = bb + t; j < be; j += 256) {
        atomicAdd(&h[(Sp[j] & 0x7FFFF) >> SLICE_SHIFT], 1);
    }
    __syncthreads();
    if (t == 0) {
        int run = bb;
#pragma unroll
        for (int s = 0; s < NSLICE; ++s) {
            soff[b * 16 + s] = run;
            run += h[s];
        }
    }
}

// ============================================================================
// fp16 table prep: x (fp32, 4 feats) -> xh (fp16, 8 B rows)
// ============================================================================

__global__ void convert_x(const float* __restrict__ x, int2* __restrict__ xh) {
    int i = blockIdx.x * 256 + threadIdx.x;
    if (i >= N_NODES) return;
    float4 v = ((const float4*)x)[i];
    int2 r;
    r.x = pk2(v.x, v.y);
    r.y = pk2(v.z, v.w);
    xh[i] = r;
}

// ============================================================================
// Edge-parallel fused layers: LDS accumulators, accum[f*512+n] layout
// (bank = n%32, node-sorted slices -> ~2-way same-address at worst)
// ============================================================================

// Layer 1: one pass (xh is 4 MB, mostly L2-resident), no phase barrier.
__global__ __launch_bounds__(256, 4) void fused_l1e(
        const int* __restrict__ bbase, const int* __restrict__ Sp,
        const int2* __restrict__ xh, const float* __restrict__ x,
        const int* __restrict__ deg,
        const float* __restrict__ wl, const float* __restrict__ bl,
        const float* __restrict__ wr, int* __restrict__ h1) {
    __shared__ float accum[4 * NPB];   // 8 KB
    __shared__ float s_wl[40];
    __shared__ float s_wr[40];
    __shared__ float s_b[10];
    int t = threadIdx.x, b = blockIdx.x;
    if (t < 40) { s_wl[t] = wl[t]; s_wr[t] = wr[t]; }
    if (t >= 64 && t < 74) s_b[t - 64] = bl[t - 64];
    for (int j = t; j < 4 * NPB; j += 256) accum[j] = 0.f;
    int lo = bbase[b], hi = bbase[b + 1];
    __syncthreads();

    for (int e = lo + t; e < hi; e += 1024) {
        int p0 = Sp[e];
        int p1 = (e + 256 < hi) ? Sp[e + 256] : -1;
        int p2 = (e + 512 < hi) ? Sp[e + 512] : -1;
        int p3 = (e + 768 < hi) ? Sp[e + 768] : -1;
        int2 v0 = xh[p0 & 0x7FFFF];
        int2 v1, v2, v3;
        if (p1 >= 0) v1 = xh[p1 & 0x7FFFF];
        if (p2 >= 0) v2 = xh[p2 & 0x7FFFF];
        if (p3 >= 0) v3 = xh[p3 & 0x7FFFF];
        {
            int n = p0 >> 19;
            float2 f0 = up2(v0.x), f1 = up2(v0.y);
            atomicAdd(&accum[0 * NPB + n], f0.x);
            atomicAdd(&accum[1 * NPB + n], f0.y);
            atomicAdd(&accum[2 * NPB + n], f1.x);
            atomicAdd(&accum[3 * NPB + n], f1.y);
        }
        if (p1 >= 0) {
            int n = p1 >> 19;
            float2 f0 = up2(v1.x), f1 = up2(v1.y);
            atomicAdd(&accum[0 * NPB + n], f0.x);
            atomicAdd(&accum[1 * NPB + n], f0.y);
            atomicAdd(&accum[2 * NPB + n], f1.x);
            atomicAdd(&accum[3 * NPB + n], f1.y);
        }
        if (p2 >= 0) {
            int n = p2 >> 19;
            float2 f0 = up2(v2.x), f1 = up2(v2.y);
            atomicAdd(&accum[0 * NPB + n], f0.x);
            atomicAdd(&accum[1 * NPB + n], f0.y);
            atomicAdd(&accum[2 * NPB + n], f1.x);
            atomicAdd(&accum[3 * NPB + n], f1.y);
        }
        if (p3 >= 0) {
            int n = p3 >> 19;
            float2 f0 = up2(v3.x), f1 = up2(v3.y);
            atomicAdd(&accum[0 * NPB + n], f0.x);
            atomicAdd(&accum[1 * NPB + n], f0.y);
            atomicAdd(&accum[2 * NPB + n], f1.x);
            atomicAdd(&accum[3 * NPB + n], f1.y);
        }
    }
    __syncthreads();

    int node0 = b << NPB_LOG;
#pragma unroll
    for (int rep = 0; rep < 2; ++rep) {
        int idx = t + rep * 256;
        int n = node0 + idx;
        if (n >= N_NODES) continue;
        float inv = 1.f / fmaxf((float)deg[n], 1.f);
        float a[4];
#pragma unroll
        for (int q = 0; q < 4; ++q) a[q] = accum[q * NPB + idx] * inv;
        float4 xs = ((const float4*)x)[n];
        float xv[4] = {xs.x, xs.y, xs.z, xs.w};
        float r[10];
#pragma unroll
        for (int j = 0; j < 10; ++j) {
            float v = s_b[j];
#pragma unroll
            for (int kk = 0; kk < 4; ++kk)
                v += s_wl[j * 4 + kk] * a[kk] + s_wr[j * 4 + kk] * xv[kk];
            r[j] = fmaxf(v, 0.f);
        }
        int4 o0;
        o0.x = pk2(r[0], r[1]); o0.y = pk2(r[2], r[3]);
        o0.z = pk2(r[4], r[5]); o0.w = pk2(r[6], r[7]);
        *(int4*)(h1 + (long)n * 8) = o0;
        h1[(long)n * 8 + 4] = pk2(r[8], r[9]);
    }
}

// Layer 2: 8 phases of 2 slices (2 MB of h1 per phase), edge-parallel.
__global__ __launch_bounds__(256, 4) void fused_l2e(
        const int* __restrict__ bbase, const int* __restrict__ sliceoff,
        const int* __restrict__ Sp, const int* __restrict__ h1,
        const int* __restrict__ deg,
        const float* __restrict__ wl, const float* __restrict__ bl,
        const float* __restrict__ wr, int* __restrict__ h2,
        int* __restrict__ bar) {
    __shared__ float accum[10 * NPB];   // 20 KB
    __shared__ float s_wl[200];
    __shared__ float s_wr[200];
    __shared__ float s_b[20];
    int t = threadIdx.x, b = blockIdx.x;
    if (t < 200) { s_wl[t] = wl[t]; s_wr[t] = wr[t]; }
    if (t >= 224 && t < 244) s_b[t - 224] = bl[t - 224];
    for (int j = t; j < 10 * NPB; j += 256) accum[j] = 0.f;
    int be = bbase[b + 1];
    __syncthreads();

    bool coop = true;
    if (t == 0) { barrier_arrive(bar, b); coop = barrier_wait(bar, ENTRY_BUDGET); }
    __syncthreads();

    for (int s = 0; s < 8; ++s) {
        int lo = sliceoff[b * 16 + 2 * s];
        int hi = (s < 7) ? sliceoff[b * 16 + 2 * s + 2] : be;
        for (int e = lo + t; e < hi; e += 512) {
            int p0 = Sp[e];
            int p1 = (e + 256 < hi) ? Sp[e + 256] : -1;
            const int* r0 = h1 + (long)(p0 & 0x7FFFF) * 8;
            int4 v40 = *(const int4*)r0;
            int v10 = r0[4];
            int4 v41; int v11;
            if (p1 >= 0) {
                const int* r1 = h1 + (long)(p1 & 0x7FFFF) * 8;
                v41 = *(const int4*)r1;
                v11 = r1[4];
            }
            {
                int n = p0 >> 19;
                float2 f0 = up2(v40.x), f1 = up2(v40.y), f2 = up2(v40.z),
                       f3 = up2(v40.w), f4 = up2(v10);
                atomicAdd(&accum[0 * NPB + n], f0.x);
                atomicAdd(&accum[1 * NPB + n], f0.y);
                atomicAdd(&accum[2 * NPB + n], f1.x);
                atomicAdd(&accum[3 * NPB + n], f1.y);
                atomicAdd(&accum[4 * NPB + n], f2.x);
                atomicAdd(&accum[5 * NPB + n], f2.y);
                atomicAdd(&accum[6 * NPB + n], f3.x);
                atomicAdd(&accum[7 * NPB + n], f3.y);
                atomicAdd(&accum[8 * NPB + n], f4.x);
                atomicAdd(&accum[9 * NPB + n], f4.y);
            }
            if (p1 >= 0) {
                int n = p1 >> 19;
                float2 f0 = up2(v41.x), f1 = up2(v41.y), f2 = up2(v41.z),
                       f3 = up2(v41.w), f4 = up2(v11);
                atomicAdd(&accum[0 * NPB + n], f0.x);
                atomicAdd(&accum[1 * NPB + n], f0.y);
                atomicAdd(&accum[2 * NPB + n], f1.x);
                atomicAdd(&accum[3 * NPB + n], f1.y);
                atomicAdd(&accum[4 * NPB + n], f2.x);
                atomicAdd(&accum[5 * NPB + n], f2.y);
                atomicAdd(&accum[6 * NPB + n], f3.x);
                atomicAdd(&accum[7 * NPB + n], f3.y);
                atomicAdd(&accum[8 * NPB + n], f4.x);
                atomicAdd(&accum[9 * NPB + n], f4.y);
            }
        }
        if (s < 7) {
            if (t == 0) {
                int* rec = bar + (1 + s) * BAR_REC_INTS;
                barrier_arrive(rec, b);
                if (coop) coop = barrier_wait(rec, PHASE_BUDGET);
            }
            __syncthreads();
        }
    }
    __syncthreads();

    int node0 = b << NPB_LOG;
#pragma unroll
    for (int rep = 0; rep < 2; ++rep) {
        int idx = t + rep * 256;
        int n = node0 + idx;
        if (n >= N_NODES) continue;
        float inv = 1.f / fmaxf((float)deg[n], 1.f);
        float a[10];
#pragma unroll
        for (int q = 0; q < 10; ++q) a[q] = accum[q * NPB + idx] * inv;
        float xv[10];
        {
            const int* row = h1 + (long)n * 8;
            int4 v4 = *(const int4*)row;
            int v1 = row[4];
            float2 f0 = up2(v4.x), f1 = up2(v4.y), f2 = up2(v4.z), f3 = up2(v4.w), f4 = up2(v1);
            xv[0] = f0.x; xv[1] = f0.y; xv[2] = f1.x; xv[3] = f1.y;
            xv[4] = f2.x; xv[5] = f2.y; xv[6] = f3.x; xv[7] = f3.y;
            xv[8] = f4.x; xv[9] = f4.y;
        }
        float r[20];
#pragma unroll
        for (int j = 0; j < 20; ++j) {
            float v = s_b[j];
#pragma unroll
            for (int kk = 0; kk < 10; ++kk)
                v += s_wl[j * 10 + kk] * a[kk] + s_wr[j * 10 + kk] * xv[kk];
            r[j] = fmaxf(v, 0.f);
        }
        int* o = h2 + (long)n * 16;
        int4 o0, o1;
        o0.x = pk2(r[0], r[1]);   o0.y = pk2(r[2], r[3]);
        o0.z = pk2(r[4], r[5]);   o0.w = pk2(r[6], r[7]);
        o1.x = pk2(r[8], r[9]);   o1.y = pk2(r[10], r[11]);
        o1.z = pk2(r[12], r[13]); o1.w = pk2(r[14], r[15]);
        *(int4*)o = o0;
        *(int4*)(o + 4) = o1;
        int2 o2;
        o2.x = pk2(r[16], r[17]); o2.y = pk2(r[18], r[19]);
        *(int2*)(o + 8) = o2;
    }
}

// Layer 3 + classifier: 16 phases of 1 slice (2 MB of h2 per phase).
// accum = 40960 B exactly -> 4 blocks/CU -> all 977 blocks co-resident.
// Weights read from global (uniform addresses, cached) - no LDS room.
__global__ __launch_bounds__(256, 4) void fused_l3e(
        const int* __restrict__ bbase, const int* __restrict__ sliceoff,
        const int* __restrict__ Sp, const int* __restrict__ h2,
        const int* __restrict__ deg,
        const float* __restrict__ w3l, const float* __restrict__ b3,
        const float* __restrict__ w3r,
        const float* __restrict__ wc, const float* __restrict__ bc,
        float* __restrict__ out, int* __restrict__ bar) {
    __shared__ float accum[20 * NPB];   // 40 KB exactly
    int t = threadIdx.x, b = blockIdx.x;
    for (int j = t; j < 20 * NPB; j += 256) accum[j] = 0.f;
    int be = bbase[b + 1];
    __syncthreads();

    bool coop = true;
    if (t == 0) { barrier_arrive(bar, b); coop = barrier_wait(bar, ENTRY_BUDGET); }
    __syncthreads();

    for (int s = 0; s < 16; ++s) {
        int lo = sliceoff[b * 16 + s];
        int hi = (s < 15) ? sliceoff[b * 16 + s + 1] : be;
        for (int e = lo + t; e < hi; e += 512) {
            int p0 = Sp[e];
            int p1 = (e + 256 < hi) ? Sp[e + 256] : -1;
            const int* r0 = h2 + (long)(p0 & 0x7FFFF) * 16;
            int4 va0 = *(const int4*)r0;
            int4 vb0 = *(const int4*)(r0 + 4);
            int2 vc0 = *(const int2*)(r0 + 8);
            int4 va1, vb1; int2 vc1;
            if (p1 >= 0) {
                const int* r1 = h2 + (long)(p1 & 0x7FFFF) * 16;
                va1 = *(const int4*)r1;
                vb1 = *(const int4*)(r1 + 4);
                vc1 = *(const int2*)(r1 + 8);
            }
            {
                int n = p0 >> 19;
                float2 f;
                f = up2(va0.x); atomicAdd(&accum[0 * NPB + n], f.x);  atomicAdd(&accum[1 * NPB + n], f.y);
                f = up2(va0.y); atomicAdd(&accum[2 * NPB + n], f.x);  atomicAdd(&accum[3 * NPB + n], f.y);
                f = up2(va0.z); atomicAdd(&accum[4 * NPB + n], f.x);  atomicAdd(&accum[5 * NPB + n], f.y);
                f = up2(va0.w); atomicAdd(&accum[6 * NPB + n], f.x);  atomicAdd(&accum[7 * NPB + n], f.y);
                f = up2(vb0.x); atomicAdd(&accum[8 * NPB + n], f.x);  atomicAdd(&accum[9 * NPB + n], f.y);
                f = up2(vb0.y); atomicAdd(&accum[10 * NPB + n], f.x); atomicAdd(&accum[11 * NPB + n], f.y);
                f = up2(vb0.z); atomicAdd(&accum[12 * NPB + n], f.x); atomicAdd(&accum[13 * NPB + n], f.y);
                f = up2(vb0.w); atomicAdd(&accum[14 * NPB + n], f.x); atomicAdd(&accum[15 * NPB + n], f.y);
                f = up2(vc0.x); atomicAdd(&accum[16 * NPB + n], f.x); atomicAdd(&accum[17 * NPB + n], f.y);
                f = up2(vc0.y); atomicAdd(&accum[18 * NPB + n], f.x); atomicAdd(&accum[19 * NPB + n], f.y);
            }
            if (p1 >= 0) {
                int n = p1 >> 19;
                float2 f;
                f = up2(va1.x); atomicAdd(&accum[0 * NPB + n], f.x);  atomicAdd(&accum[1 * NPB + n], f.y);
                f = up2(va1.y); atomicAdd(&accum[2 * NPB + n], f.x);  atomicAdd(&accum[3 * NPB + n], f.y);
                f = up2(va1.z); atomicAdd(&accum[4 * NPB + n], f.x);  atomicAdd(&accum[5 * NPB + n], f.y);
                f = up2(va1.w); atomicAdd(&accum[6 * NPB + n], f.x);  atomicAdd(&accum[7 * NPB + n], f.y);
                f = up2(vb1.x); atomicAdd(&accum[8 * NPB + n], f.x);  atomicAdd(&accum[9 * NPB + n], f.y);
                f = up2(vb1.y); atomicAdd(&accum[10 * NPB + n], f.x); atomicAdd(&accum[11 * NPB + n], f.y);
                f = up2(vb1.z); atomicAdd(&accum[12 * NPB + n], f.x); atomicAdd(&accum[13 * NPB + n], f.y);
                f = up2(vb1.w); atomicAdd(&accum[14 * NPB + n], f.x); atomicAdd(&accum[15 * NPB + n], f.y);
                f = up2(vc1.x); atomicAdd(&accum[16 * NPB + n], f.x); atomicAdd(&accum[17 * NPB + n], f.y);
                f = up2(vc1.y); atomicAdd(&accum[18 * NPB + n], f.x); atomicAdd(&accum[19 * NPB + n], f.y);
            }
        }
        if (s < 15) {
            if (t == 0) {
                int* rec = bar + (1 + s) * BAR_REC_INTS;
                barrier_arrive(rec, b);
                if (coop) coop = barrier_wait(rec, PHASE_BUDGET);
            }
            __syncthreads();
        }
    }
    __syncthreads();

    int node0 = b << NPB_LOG;
#pragma unroll
    for (int rep = 0; rep < 2; ++rep) {
        int idx = t + rep * 256;
        int n = node0 + idx;
        if (n >= N_NODES) continue;
        float inv = 1.f / fmaxf((float)deg[n], 1.f);
        float a[20];
#pragma unroll
        for (int q = 0; q < 20; ++q) a[q] = accum[q * NPB + idx] * inv;
        float xv[20];
        {
            const int* row = h2 + (long)n * 16;
            int4 va = *(const int4*)row;
            int4 vb = *(const int4*)(row + 4);
            int2 vc = *(const int2*)(row + 8);
            float2 f;
            f = up2(va.x); xv[0] = f.x; xv[1] = f.y;
            f = up2(va.y); xv[2] = f.x; xv[3] = f.y;
            f = up2(va.z); xv[4] = f.x; xv[5] = f.y;
            f = up2(va.w); xv[6] = f.x; xv[7] = f.y;
            f = up2(vb.x); xv[8] = f.x; xv[9] = f.y;
            f = up2(vb.y); xv[10] = f.x; xv[11] = f.y;
            f = up2(vb.z); xv[12] = f.x; xv[13] = f.y;
            f = up2(vb.w); xv[14] = f.x; xv[15] = f.y;
            f = up2(vc.x); xv[16] = f.x; xv[17] = f.y;
            f = up2(vc.y); xv[18] = f.x; xv[19] = f.y;
        }
        float h3[20];
#pragma unroll
        for (int j = 0; j < 20; ++j) {
            float r = b3[j];
#pragma unroll
            for (int kk = 0; kk < 20; ++kk)
                r += w3l[j * 20 + kk] * a[kk] + w3r[j * 20 + kk] * xv[kk];
            h3[j] = fmaxf(r, 0.f);
        }
#pragma unroll
        for (int j = 0; j < 8; ++j) {
            float r = bc[j];
#pragma unroll
            for (int kk = 0; kk < 20; ++kk) r += wc[j * 20 + kk] * h3[kk];
            out[(long)n * 8 + j] = r;
        }
    }
}

// ============================================================================
// Path B (fallback, small ws): float-atomic version
// ============================================================================

__global__ void deg_kernel(const int* __restrict__ dst, int* __restrict__ deg) {
    int i = blockIdx.x * blockDim.x + threadIdx.x;
    if (i < N_EDGES) atomicAdd(&deg[dst[i]], 1);
}

template <int F>
__global__ void edge_agg(const int* __restrict__ src, const int* __restrict__ dst,
                         const float* __restrict__ h, float* __restrict__ agg) {
    int i = blockIdx.x * blockDim.x + threadIdx.x;
    if (i >= N_EDGES) return;
    int s = src[i];
    int d = dst[i];
    const float* hs = h + (long)s * F;
    float* ad = agg + (long)d * F;
#pragma unroll
    for (int f = 0; f < F; ++f) atomicAdd(&ad[f], hs[f]);
}

template <int FIN, int FOUT>
__global__ void node_apply(const float* __restrict__ agg, const float* __restrict__ hin,
                           const int* __restrict__ deg, const float* __restrict__ wl,
                           const float* __restrict__ bl, const float* __restrict__ wr,
                           float* __restrict__ hout) {
    __shared__ float s_wl[FOUT * FIN];
    __shared__ float s_wr[FOUT * FIN];
    __shared__ float s_b[FOUT];
    for (int t = threadIdx.x; t < FOUT * FIN; t += blockDim.x) {
        s_wl[t] = wl[t];
        s_wr[t] = wr[t];
    }
    for (int t = threadIdx.x; t < FOUT; t += blockDim.x) s_b[t] = bl[t];
    __syncthreads();
    int i = blockIdx.x * blockDim.x + threadIdx.x;
    if (i >= N_NODES) return;
    float inv = 1.0f / fmaxf((float)deg[i], 1.0f);
    float a[FIN], xv[FIN];
#pragma unroll
    for (int kk = 0; kk < FIN; ++kk) {
        a[kk] = agg[(long)i * FIN + kk] * inv;
        xv[kk] = hin[(long)i * FIN + kk];
    }
#pragma unroll
    for (int j = 0; j < FOUT; ++j) {
        float r = s_b[j];
#pragma unroll
        for (int kk = 0; kk < FIN; ++kk) r += s_wl[j * FIN + kk] * a[kk] + s_wr[j * FIN + kk] * xv[kk];
        hout[(long)i * FOUT + j] = fmaxf(r, 0.f);
    }
}

__global__ void node_final_old(const float* __restrict__ agg, const float* __restrict__ hin,
                               const int* __restrict__ deg, const float* __restrict__ w3l,
                               const float* __restrict__ b3, const float* __restrict__ w3r,
                               const float* __restrict__ wc, const float* __restrict__ bc,
                               float* __restrict__ out) {
    __shared__ float s_wl[400];
    __shared__ float s_wr[400];
    __shared__ float s_b[20];
    __shared__ float s_wc[160];
    __shared__ float s_bc[8];
    for (int t = threadIdx.x; t < 400; t += blockDim.x) {
        s_wl[t] = w3l[t];
        s_wr[t] = w3r[t];
    }
    for (int t = threadIdx.x; t < 160; t += blockDim.x) s_wc[t] = wc[t];
    for (int t = threadIdx.x; t < 20; t += blockDim.x) s_b[t] = b3[t];
    for (int t = threadIdx.x; t < 8; t += blockDim.x) s_bc[t] = bc[t];
    __syncthreads();
    int i = blockIdx.x * blockDim.x + threadIdx.x;
    if (i >= N_NODES) return;
    float inv = 1.0f / fmaxf((float)deg[i], 1.0f);
    float a[20], xv[20];
#pragma unroll
    for (int kk = 0; kk < 20; ++kk) {
        a[kk] = agg[(long)i * 20 + kk] * inv;
        xv[kk] = hin[(long)i * 20 + kk];
    }
    float h3[20];
#pragma unroll
    for (int j = 0; j < 20; ++j) {
        float r = s_b[j];
#pragma unroll
        for (int kk = 0; kk < 20; ++kk) r += s_wl[j * 20 + kk] * a[kk] + s_wr[j * 20 + kk] * xv[kk];
        h3[j] = fmaxf(r, 0.f);
    }
#pragma unroll
    for (int j = 0; j < 8; ++j) {
        float r = s_bc[j];
#pragma unroll
        for (int kk = 0; kk < 20; ++kk) r += s_wc[j * 20 + kk] * h3[kk];
        out[(long)i * 8 + j] = r;
    }
}

// ============================================================================

extern "C" void kernel_launch(void* const* d_in, const int* in_sizes, int n_in,
                              void* d_out, int out_size, void* d_ws, size_t ws_size,
                              hipStream_t stream) {
    const float* x = (const float*)d_in[0];
    const int* ei = (const int*)d_in[1];  // [2, E]: src row then dst row
    const float* w1l = (const float*)d_in[2];
    const float* b1 = (const float*)d_in[3];
    const float* w1r = (const float*)d_in[4];
    const float* w2l = (const float*)d_in[5];
    const float* b2 = (const float*)d_in[6];
    const float* w2r = (const float*)d_in[7];
    const float* w3l = (const float*)d_in[8];
    const float* b3 = (const float*)d_in[9];
    const float* w3r = (const float*)d_in[10];
    const float* wc = (const float*)d_in[11];
    const float* bc = (const float*)d_in[12];
    float* out = (float*)d_out;

    const int* src = ei;
    const int* dst = ei + N_EDGES;

    const int BT = 256;
    dim3 blk(BT);
    dim3 egrid((N_EDGES + BT - 1) / BT);
    dim3 ngrid(NB);

    // ---- Path A v14 layout (bytes):
    // deg      [0,          2,000,000)   500K ints  (written by fine_sort; OUTSIDE P)
    // bbase    [2,000,128,  2,004,352)   1025 ints (padded)
    // gcur     [2,004,352,  2,008,448)   1024 ints
    // P        [2,008,448,  66,008,448)  16M packed ints (dead after fine_sort)
    //   xh     [2,008,448,  6,008,448)   overlay: 500K x 8 B fp16 rows
    //   h1     [6,008,448, 22,008,448)   overlay: 500K x 32 B fp16 rows
    //   h2     [22,008,448, 54,008,448)  overlay: 500K x 64 B fp16 rows
    //   bar    [54,008,448, 54,106,752)  overlay: 24 x 4 KB barrier records
    //   soff   [54,206,464, 54,269,000)  overlay: 977 x 16 slice offsets
    //          (bar/soff written only AFTER fine_sort, when P is dead)
    // Sp       [66,008,448, 130,008,448) 16M packed (node<<19|src), slice-major
    const size_t NEED_A = 130008448;

    if (ws_size >= NEED_A) {
        char* ws = (char*)d_ws;
        int* deg = (int*)ws;
        int* bbase = (int*)(ws + 2000128);
        int* gcur = (int*)(ws + 2004352);
        int* P = (int*)(ws + 2008448);
        int2* xh = (int2*)(ws + 2008448);
        int* h1 = (int*)(ws + 6008448);
        int* h2 = (int*)(ws + 22008448);
        int* bar2 = (int*)(ws + 54008448);               // 8 records (entry + 7)
        int* bar3 = bar2 + 8 * BAR_REC_INTS;             // 16 records (entry + 15)
        int* soff = (int*)(ws + 54206464);
        int* Sp = (int*)(ws + 66008448);

        hipMemsetAsync(gcur, 0, NBUCK_PAD * sizeof(int), stream);
        bucket_hist<<<1024, blk, 0, stream>>>(dst, gcur);
        bucket_scan<<<1, blk, 0, stream>>>(gcur, bbase);
        bucket_scatter<<<NSB, blk, 0, stream>>>(src, dst, gcur, P);
        fine_sort<<<NBUCK, blk, 0, stream>>>(P, bbase, deg, Sp);

        // P region is dead after fine_sort; overlays become writable.
        hipMemsetAsync(bar2, 0, 24 * BAR_REC_INTS * sizeof(int), stream);
        slice_off<<<NBUCK, blk, 0, stream>>>(bbase, Sp, soff);

        convert_x<<<ngrid, blk, 0, stream>>>(x, xh);
        fused_l1e<<<NBUCK, blk, 0, stream>>>(bbase, Sp, xh, x, deg, w1l, b1, w1r, h1);
        fused_l2e<<<NBUCK, blk, 0, stream>>>(bbase, soff, Sp, h1, deg, w2l, b2, w2r, h2, bar2);
        fused_l3e<<<NBUCK, blk, 0, stream>>>(bbase, soff, Sp, h2, deg, w3l, b3, w3r, wc, bc, out, bar3);
    } else {
        // fallback: float-atomic path (needs 102 MB)
        char* ws = (char*)d_ws;
        int* deg = (int*)ws;
        float* agg = (float*)(ws + 2000000);
        float* h1 = (float*)(ws + 42000000);
        float* h2 = (float*)(ws + 62000000);

        hipMemsetAsync(deg, 0, (size_t)N_NODES * sizeof(int), stream);
        deg_kernel<<<egrid, blk, 0, stream>>>(dst, deg);

        hipMemsetAsync(agg, 0, (size_t)N_NODES * 4 * sizeof(float), stream);
        edge_agg<4><<<egrid, blk, 0, stream>>>(src, dst, x, agg);
        node_apply<4, 10><<<ngrid, blk, 0, stream>>>(agg, x, deg, w1l, b1, w1r, h1);

        hipMemsetAsync(agg, 0, (size_t)N_NODES * 10 * sizeof(float), stream);
        edge_agg<10><<<egrid, blk, 0, stream>>>(src, dst, h1, agg);
        node_apply<10, 20><<<ngrid, blk, 0, stream>>>(agg, h1, deg, w2l, b2, w2r, h2);

        hipMemsetAsync(agg, 0, (size_t)N_NODES * 20 * sizeof(float), stream);
        edge_agg<20><<<egrid, blk, 0, stream>>>(src, dst, h2, agg);
        node_final_old<<<ngrid, blk, 0, stream>>>(agg, h2, deg, w3l, b3, w3r, wc, bc, out);
    }
}